// Round 1
// 286.279 us; speedup vs baseline: 1.0501x; 1.0501x over previous
//
#include <hip/hip_runtime.h>
#include <cstdint>
#include <cstddef>
#include <cmath>

// ---------------------------------------------------------------------------
// Types
// ---------------------------------------------------------------------------
typedef __bf16 bf16x8 __attribute__((ext_vector_type(8)));   // K=32 MFMA A/B frag
typedef float  f32x4  __attribute__((ext_vector_type(4)));   // MFMA C/D frag
typedef unsigned short us4 __attribute__((ext_vector_type(4)));

// float -> bf16, round-to-nearest-even
__device__ __forceinline__ unsigned short f2bf(float f) {
    union { float f; unsigned int u; } v; v.f = f;
    unsigned int u = v.u;
    u += 0x7fffu + ((u >> 16) & 1u);
    return (unsigned short)(u >> 16);
}

__device__ __forceinline__ unsigned int fbits(float f) {
    union { float f; unsigned int u; } v; v.f = f; return v.u;
}

// pack two f32 -> bf16x2 (truncate) in ONE v_perm_b32: low = a, high = b
__device__ __forceinline__ unsigned int pk_bf16_trunc(float a, float b) {
    return __builtin_amdgcn_perm(fbits(b), fbits(a), 0x07060302u);
}

// async global->LDS, 16B per lane; LDS dest = wave-uniform base + lane*16
__device__ __forceinline__ void gld_lds16(const void* g, void* l) {
    __builtin_amdgcn_global_load_lds((__attribute__((address_space(1))) void*)g,
                                     (__attribute__((address_space(3))) void*)l,
                                     16, 0, 0);
}

// ---------------------------------------------------------------------------
// Problem constants
// ---------------------------------------------------------------------------
#define BB   2
#define SS   2048
#define DD   2048
#define HQ   32
#define HKV  8
#define DH   64
#define MM   (BB * SS)          // 4096 tokens
#define NQKV 3072               // 2048 q + 512 k + 512 v

// 0.125 (1/sqrt(DH)) * log2(e) — folded into Wq at transpose_cast2 time so the
// QK^T MFMA output is directly the exp2 argument (softmax shift-invariance
// makes the old "-8" bias a pure 2^-8 factor that cancels in o/l; dropped).
#define QSCALE 0.18033688011112042f

// ---------------------------------------------------------------------------
// Kernel: fp32 -> bf16 cast (vectorized)
// ---------------------------------------------------------------------------
__global__ __launch_bounds__(256) void cast_f32_bf16(const float* __restrict__ src,
                                                     unsigned short* __restrict__ dst,
                                                     int n) {
    int i = (blockIdx.x * 256 + threadIdx.x) * 4;
    if (i >= n) return;
    const float4 f = *(const float4*)(src + i);
    us4 o;
    o[0] = f2bf(f.x); o[1] = f2bf(f.y); o[2] = f2bf(f.z); o[3] = f2bf(f.w);
    *(us4*)(dst + i) = o;
}

// ---------------------------------------------------------------------------
// Kernel: batched transpose + cast + scale, 2 matrices per launch (z selects)
// src[R][C] f32 -> dst[C][R] bf16 * scale.  grid = (C/32, R/32, 2), block = 256
// ---------------------------------------------------------------------------
__global__ __launch_bounds__(256) void transpose_cast2(const float* __restrict__ srcA,
                                                       const float* __restrict__ srcB,
                                                       unsigned short* __restrict__ dstA,
                                                       unsigned short* __restrict__ dstB,
                                                       int R, int C,
                                                       float sA, float sB) {
    __shared__ __attribute__((aligned(16))) float tile[32][33];
    const float* src = blockIdx.z ? srcB : srcA;
    unsigned short* dst = blockIdx.z ? dstB : dstA;
    const float scl = blockIdx.z ? sB : sA;
    const int c0 = blockIdx.x * 32, r0 = blockIdx.y * 32;
    const int tx = threadIdx.x & 31, ty = threadIdx.x >> 5;
    #pragma unroll
    for (int dy = 0; dy < 32; dy += 8)
        tile[ty + dy][tx] = src[(size_t)(r0 + ty + dy) * C + c0 + tx];
    __syncthreads();
    #pragma unroll
    for (int dy = 0; dy < 32; dy += 8)
        dst[(size_t)(c0 + ty + dy) * R + r0 + tx] = f2bf(tile[tx][ty + dy] * scl);
}

// ---------------------------------------------------------------------------
// Kernel: transpose V slice of QKV into Vt[b][kvh][d][s]  (bf16 -> bf16)
// grid = (S/32, DH/32, B*HKV), block = 256 (32x8)
// ---------------------------------------------------------------------------
__global__ __launch_bounds__(256) void transpose_v(const unsigned short* __restrict__ qkv,
                                                   unsigned short* __restrict__ vt) {
    __shared__ __attribute__((aligned(16))) unsigned short tile[32][33];
    const int s0 = blockIdx.x * 32, d0 = blockIdx.y * 32;
    const int bh = blockIdx.z;
    const int b = bh >> 3, kvh = bh & 7;
    const int tx = threadIdx.x & 31, ty = threadIdx.x >> 5;
    #pragma unroll
    for (int dy = 0; dy < 32; dy += 8)
        tile[ty + dy][tx] =
            qkv[(size_t)(b * SS + s0 + ty + dy) * NQKV + 2560 + kvh * DH + d0 + tx];
    __syncthreads();
    #pragma unroll
    for (int dy = 0; dy < 32; dy += 8)
        vt[(size_t)((b * HKV + kvh) * DH + d0 + ty + dy) * SS + s0 + tx] =
            tile[tx][ty + dy];
}

// ---------------------------------------------------------------------------
// Kernel: bf16 GEMM, C[M][N] = A[M][K] * Bt[N][K]^T
// 128x128 tile, BK=64, 4 waves (2x2 of 64x64), 16x16x32 MFMA.
// LDS chunk-XOR swizzle -> conflict-free b128 frag reads w/ gld_lds16 staging.
// ---------------------------------------------------------------------------
template <int OUT_BF16>
__global__ __launch_bounds__(256) void gemm_bt(const unsigned short* __restrict__ A,
                                               const unsigned short* __restrict__ Bt,
                                               void* __restrict__ Cout,
                                               int M, int N, int K) {
    __shared__ __attribute__((aligned(16))) unsigned short As[128 * 64];
    __shared__ __attribute__((aligned(16))) unsigned short Bs[128 * 64];
    const int bm = blockIdx.x, bn = blockIdx.y;
    const int tid = threadIdx.x;
    const int wave = tid >> 6, lane = tid & 63;
    const int wm = (wave >> 1) * 64, wn = (wave & 1) * 64;
    const int g = lane >> 4, l15 = lane & 15;
    const int sr = lane >> 3;
    const int sc8 = ((lane & 7) ^ (sr & 7)) * 8;   // swizzled source chunk
    const int r7 = l15 & 7;

    f32x4 acc[4][4] = {};
    const unsigned short* aBase = A  + (size_t)(bm * 128) * K;
    const unsigned short* bBase = Bt + (size_t)(bn * 128) * K;

    for (int kt = 0; kt < K; kt += 64) {
        __syncthreads();
        #pragma unroll
        for (int j = 0; j < 4; ++j) {
            const int i = wave * 4 + j;                      // wave-uniform
            gld_lds16(aBase + (size_t)(i * 8 + sr) * K + kt + sc8, &As[i * 512]);
            gld_lds16(bBase + (size_t)(i * 8 + sr) * K + kt + sc8, &Bs[i * 512]);
        }
        __syncthreads();
        #pragma unroll
        for (int ks = 0; ks < 2; ++ks) {
            bf16x8 af[4], bfr[4];
            #pragma unroll
            for (int t = 0; t < 4; ++t) {
                af[t]  = *(const bf16x8*)&As[(wm + t * 16 + l15) * 64 + ((ks * 4 + g) ^ r7) * 8];
                bfr[t] = *(const bf16x8*)&Bs[(wn + t * 16 + l15) * 64 + ((ks * 4 + g) ^ r7) * 8];
            }
            #pragma unroll
            for (int i = 0; i < 4; ++i)
                #pragma unroll
                for (int j = 0; j < 4; ++j)
                    acc[i][j] = __builtin_amdgcn_mfma_f32_16x16x32_bf16(
                        af[i], bfr[j], acc[i][j], 0, 0, 0);
        }
    }
    // epilogue: C/D layout col = lane&15, row = (lane>>4)*4 + reg
    #pragma unroll
    for (int i = 0; i < 4; ++i) {
        #pragma unroll
        for (int j = 0; j < 4; ++j) {
            const int col = bn * 128 + wn + j * 16 + l15;
            #pragma unroll
            for (int r = 0; r < 4; ++r) {
                const int row = bm * 128 + wm + i * 16 + g * 4 + r;
                const float v = acc[i][j][r];
                if (OUT_BF16)
                    ((unsigned short*)Cout)[(size_t)row * N + col] = f2bf(v);
                else
                    ((float*)Cout)[(size_t)row * N + col] = v;
            }
        }
    }
}

// ---------------------------------------------------------------------------
// Kernel: flash attention v8 — register-resident P at K=32, VALU-lean softmax.
// v7 -> v8 deltas (VALU was the bottleneck: VALUBusy 41% > MfmaUtil 31%):
//  * softmax scale folded into Wq upstream -> pe = exp2(c) directly, no
//    fma/bias on the QK output (the old -8 bias is a pure 2^-8 factor that
//    cancels in o/l; scores bounded, no bf16 overflow risk).
//  * denominator via ones-vector MFMA (lacc[m] = P @ 1) instead of per-lane
//    f32x4 adds: 8 extra MFMAs/tile on the idle matrix pipe replace 64 v_add
//    on the saturated VALU pipe. Bonus: C/D layout (row = g*4+r) puts each
//    q-row's sum in exactly the lane/reg holding that row's O accumulator,
//    so the shuffle-reduce epilogue disappears. VGPR-neutral (rl4 out).
//  * s_setprio(1) around the PV MFMA cluster (T5, measured + on attn).
// grid = (S/256, HQ, B), block = 256 (4 waves x 64 q)
// ---------------------------------------------------------------------------
__global__ __launch_bounds__(256, 2) void flash_attn(const unsigned short* __restrict__ qkv,
                                                     const unsigned short* __restrict__ vt,
                                                     unsigned short* __restrict__ ctx) {
    __shared__ __attribute__((aligned(16))) unsigned short Ks[2][64 * 64];   // [permuted key][dh] swz
    __shared__ __attribute__((aligned(16))) unsigned short Vs[2][64 * 64];   // [dh][key] swz

    const int qt = blockIdx.x, h = blockIdx.y, b = blockIdx.z;
    const int kvh = h >> 2;   // NUM_REP = 4
    const int tid = threadIdx.x, wave = tid >> 6, lane = tid & 63;
    const int g = lane >> 4, l15 = lane & 15;
    const int sr = lane >> 3;
    const int sc8 = ((lane & 7) ^ (sr & 7)) * 8;
    const int r7 = l15 & 7;
    const int qb = qt * 256 + wave * 64;

    const unsigned short* kbase = qkv + (size_t)(b * SS) * NQKV + 2048 + kvh * DH;
    const unsigned short* vbase = vt + (size_t)((b * HKV + kvh) * DH) * SS;

    // Q fragments, B-operand layout (n-col = l15, k = g*8+j): [q n-tile][k-half]
    bf16x8 qf[4][2];
    #pragma unroll
    for (int n = 0; n < 4; ++n)
        #pragma unroll
        for (int kh = 0; kh < 2; ++kh)
            qf[n][kh] = *(const bf16x8*)(qkv +
                (size_t)(b * SS + qb + n * 16 + l15) * NQKV + h * DH + kh * 32 + g * 8);

    // all-ones B fragment for the denominator MFMA (any layout: every elem 1)
    bf16x8 ones;
    #pragma unroll
    for (int i = 0; i < 8; ++i) ones[i] = (__bf16)1.0f;

    // per-lane staging pointers (advanced by constant each iter; no per-iter mul)
    const unsigned short* sp[4];
    size_t sadv;
    if (wave < 2) {
        #pragma unroll
        for (int j = 0; j < 4; ++j) {
            const int rho = (wave * 4 + j) * 8 + sr;       // LDS row this lane fills
            // bit-swap: rho=[p,h,g1,g0,r1,r0] -> physical key=[p,g1,g0,h,r1,r0]
            const int key = (rho & 0x23) | ((rho & 0x0C) << 1) | ((rho & 0x10) >> 2);
            sp[j] = kbase + (size_t)key * NQKV + sc8;
        }
        sadv = (size_t)64 * NQKV;          // next 64 keys
    } else {
        #pragma unroll
        for (int j = 0; j < 4; ++j)
            sp[j] = vbase + (size_t)(((wave - 2) * 4 + j) * 8 + sr) * SS + sc8;
        sadv = 64;                          // next 64 keys (columns of Vt)
    }

    #define STAGE(buf)                                                        \
        do {                                                                  \
            if (wave < 2) {                                                   \
                _Pragma("unroll")                                             \
                for (int j = 0; j < 4; ++j)                                   \
                    gld_lds16(sp[j], &Ks[buf][(wave * 4 + j) * 512]);         \
            } else {                                                          \
                _Pragma("unroll")                                             \
                for (int j = 0; j < 4; ++j)                                   \
                    gld_lds16(sp[j], &Vs[buf][((wave - 2) * 4 + j) * 512]);   \
            }                                                                 \
            _Pragma("unroll")                                                 \
            for (int j = 0; j < 4; ++j) sp[j] += sadv;                        \
        } while (0)

    f32x4 oacc[4][4] = {};        // [q m-tile][dh n-tile]
    f32x4 lacc[4] = {};           // denominator accum: lacc[m][r] = rowsum(q=m*16+g*4+r)

    STAGE(0);
    int cur = 0;

    for (int kt = 0; kt < SS; kt += 64) {
        // compiler emits s_waitcnt vmcnt(0) before s_barrier -> buf[cur] ready
        __syncthreads();
        if (kt + 64 < SS) { STAGE(cur ^ 1); }   // prefetch hidden behind compute

        const unsigned short* ks = Ks[cur];
        const unsigned short* vs = Vs[cur];

        // per 32-key chunk p: two Sᵀ tiles (QK K=32) -> exp -> concat packs
        // ARE the K=32 P A-frag -> PV at K=32
        #pragma unroll
        for (int p = 0; p < 2; ++p) {
            uint4 pk4[4];                       // P A-frags being assembled
            #pragma unroll
            for (int hh = 0; hh < 2; ++hh) {
                const int t = 2 * p + hh;
                bf16x8 kf0 = *(const bf16x8*)&ks[(t * 16 + l15) * 64 + ((g) ^ r7) * 8];
                bf16x8 kf1 = *(const bf16x8*)&ks[(t * 16 + l15) * 64 + ((4 + g) ^ r7) * 8];
                #pragma unroll
                for (int n = 0; n < 4; ++n) {
                    f32x4 c = {};
                    c = __builtin_amdgcn_mfma_f32_16x16x32_bf16(kf0, qf[n][0], c, 0, 0, 0);
                    c = __builtin_amdgcn_mfma_f32_16x16x32_bf16(kf1, qf[n][1], c, 0, 0, 0);
                    // Wq pre-scaled by 0.125*log2(e): c IS the exp2 argument
                    f32x4 pe;
                    pe[0] = __builtin_amdgcn_exp2f(c[0]);
                    pe[1] = __builtin_amdgcn_exp2f(c[1]);
                    pe[2] = __builtin_amdgcn_exp2f(c[2]);
                    pe[3] = __builtin_amdgcn_exp2f(c[3]);
                    const unsigned int lo = pk_bf16_trunc(pe[0], pe[1]);
                    const unsigned int hi = pk_bf16_trunc(pe[2], pe[3]);
                    if (hh == 0) { pk4[n].x = lo; pk4[n].y = hi; }
                    else         { pk4[n].z = lo; pk4[n].w = hi; }
                }
            }
            // O += P(p) @ V(p) at K=32: A = P regs, B = Vs[dh][keys p*32+g*8..+7]
            // denominator rides along: lacc[m] += P(p) @ 1 (matrix pipe, not VALU)
            __builtin_amdgcn_s_setprio(1);
            #pragma unroll
            for (int nt = 0; nt < 4; ++nt) {
                bf16x8 vf = *(const bf16x8*)&vs[(nt * 16 + l15) * 64 +
                                                (((p << 2) + g) ^ r7) * 8];
                #pragma unroll
                for (int m = 0; m < 4; ++m) {
                    union { uint4 u; bf16x8 v; } pa; pa.u = pk4[m];
                    oacc[m][nt] = __builtin_amdgcn_mfma_f32_16x16x32_bf16(
                        pa.v, vf, oacc[m][nt], 0, 0, 0);
                    if (nt == 0)
                        lacc[m] = __builtin_amdgcn_mfma_f32_16x16x32_bf16(
                            pa.v, ones, lacc[m], 0, 0, 0);
                }
            }
            __builtin_amdgcn_s_setprio(0);
        }
        cur ^= 1;
    }

    // normalize + write: lane (g,l15) holds O[q = m*16+g*4+r][dh = nt*16+l15];
    // lacc[m][r] is the matching row denominator in the SAME lane (ones-MFMA
    // C/D layout row = g*4+r) -> no cross-lane reduce needed.
    #pragma unroll
    for (int m = 0; m < 4; ++m) {
        #pragma unroll
        for (int r = 0; r < 4; ++r) {
            const float inv = 1.0f / lacc[m][r];
            const int token = b * SS + qb + m * 16 + g * 4 + r;
            #pragma unroll
            for (int nt = 0; nt < 4; ++nt)
                ctx[(size_t)token * (HQ * DH) + h * DH + nt * 16 + l15] =
                    f2bf(oacc[m][nt][r] * inv);
        }
    }
    #undef STAGE
}

// ---------------------------------------------------------------------------
// Launcher
// ---------------------------------------------------------------------------
extern "C" void kernel_launch(void* const* d_in, const int* in_sizes, int n_in,
                              void* d_out, int out_size, void* d_ws, size_t ws_size,
                              hipStream_t stream) {
    (void)in_sizes; (void)n_in; (void)out_size; (void)ws_size;
    const float* x  = (const float*)d_in[0];
    const float* Wq = (const float*)d_in[1];
    const float* Wk = (const float*)d_in[2];
    const float* Wv = (const float*)d_in[3];
    const float* Wo = (const float*)d_in[4];
    float* out = (float*)d_out;

    char* ws = (char*)d_ws;
    unsigned short* xb     = (unsigned short*)(ws);                         // 16 MB
    unsigned short* WqkvT  = (unsigned short*)(ws + 16777216);              // 12 MB  [3072][2048]
    unsigned short* WoT    = (unsigned short*)(ws + 29360128);              // 8 MB   [2048][2048]
    unsigned short* QKV    = (unsigned short*)(ws + 37748736);              // 24 MB  [4096][3072]
    unsigned short* Vt     = (unsigned short*)(ws + 62914560);              // 4 MB   [16][64][2048]
    unsigned short* ctx    = (unsigned short*)(ws + 67108864);              // 16 MB  [4096][2048]
    // total 80 MB

    // 1) casts / transposes (batched: Wq+Wo, then Wk+Wv).
    //    Wq is pre-scaled by 0.125*log2(e) so flash_attn's QK output feeds
    //    exp2 directly (softmax is shift/scale-consistent; see kernel note).
    cast_f32_bf16<<<8192, 256, 0, stream>>>(x, xb, MM * DD);
    transpose_cast2<<<dim3(64, 64, 2), 256, 0, stream>>>(Wq, Wo, WqkvT, WoT, 2048, 2048,
                                                         QSCALE, 1.0f);
    transpose_cast2<<<dim3(16, 64, 2), 256, 0, stream>>>(
        Wk, Wv, WqkvT + (size_t)2048 * 2048, WqkvT + (size_t)2560 * 2048, 2048, 512,
        1.0f, 1.0f);

    // 2) fused QKV projection: [4096,2048] @ [2048,3072] -> QKV bf16
    gemm_bt<1><<<dim3(32, 24), 256, 0, stream>>>(xb, WqkvT, QKV, MM, NQKV, DD);

    // 3) V transpose for PV fragment layout
    transpose_v<<<dim3(64, 2, 16), 256, 0, stream>>>(QKV, Vt);

    // 4) flash attention v8 -> ctx bf16
    flash_attn<<<dim3(8, 32, 2), 256, 0, stream>>>(QKV, Vt, ctx);

    // 5) output projection: [4096,2048] @ [2048,2048] -> out fp32
    gemm_bt<0><<<dim3(32, 16), 256, 0, stream>>>(ctx, WoT, out, MM, DD, DD);
}